// Round 6
// baseline (196.489 us; speedup 1.0000x reference)
//
#include <hip/hip_runtime.h>
#include <math.h>

#define NB 4
#define DD 128
#define HH 128
#define WW 128
#define VOX (DD*HH*WW)          // 2097152 = 2^21
#define NVOX (NB*VOX)           // 8388608

struct GaussW { float w[7]; };

__device__ __forceinline__ float4 f4zero() { float4 z; z.x = z.y = z.z = z.w = 0.f; return z; }

// Async global->LDS, 16B per lane. HW semantics: LDS dest = wave-uniform base
// + lane*16 (guide §5); global src is per-lane. All callers pass a base that
// is uniform across the wave (derived from wid/t only) covering a 1024B pair
// of 512B rows; lanes 0-31 fill row r0, lanes 32-63 fill row r0+1.
__device__ __forceinline__ void gll16(const float* g, float* l) {
    __builtin_amdgcn_global_load_lds(
        (const __attribute__((address_space(1))) unsigned int*)g,
        (__attribute__((address_space(3))) unsigned int*)l, 16, 0, 0);
}

// ---------------------------------------------------------------------------
// Dual-mode fused kernel, 512 threads, one (n, z, y-slab=16) slab per block.
//   blocks [0,4096):    stage d rows via global_load_lds        -> y -> x -> P
//   blocks [4096,8192): stage u/v/w planes via global_load_lds,
//                       |curl| from LDS                         -> y -> x -> Q
// R12 analysis: VGPR=56 proved the compiler re-serialized the register-staged
// curl loads (3 dependent latency rounds, 35% HBM / 24% VALU -> latency-bound).
// global_load_lds keeps every staging load in flight with zero VGPR cost; the
// |curl| math then runs on LDS only. LDS 72704 B -> 2 blocks/CU.
__global__ __launch_bounds__(512, 2)
void yx_curl_dual_kernel(const float* __restrict__ dIn, float* __restrict__ P,
                         const float* __restrict__ v,   float* __restrict__ Q,
                         GaussW gw) {
    // 5 curl-input buffers x 24 rows x 128 floats (rows gy = y0-3 .. y0+20):
    //   buf0 = w(z), buf1 = u(z), buf2 = v(z), buf3 = v(z+dz), buf4 = u(z+dz)
    __shared__ __attribute__((aligned(16))) float stage[120 * 128];  // 61440 B
    __shared__ __attribute__((aligned(16))) float in_t[22][128];     // 11264 B

    const int NT = 512;
    int bb = blockIdx.x;               // 8192
    bool isCurl = (bb >= 4096);
    int b  = bb & 4095;
    int yq = b & 7;
    int z  = (b >> 3) & 127;
    int n  = b >> 10;
    int y0 = yq << 4;
    size_t zoff  = (size_t)z << 14;
    size_t slice = (((size_t)n << 7) | (size_t)z) << 14;
    int tid  = threadIdx.x;
    int wid  = tid >> 6;               // wave id 0..7 (uniform per wave)
    int lane = tid & 63;
    int lrow = lane >> 5;              // which row of the wave's 2-row pair
    int lcol = (lane & 31) << 2;       // float col (16B per lane)

    if (!isCurl) {
        // ---- stage 22 d rows (11 pairs) straight into in_t ----
#pragma unroll
        for (int t = 0; t < 2; ++t) {
            int pr = wid + (t << 3);
            if (pr < 11) {
                int r0 = pr << 1;
                int gy = y0 - 3 + r0 + lrow;
                gy = min(127, max(0, gy));
                gll16(dIn + slice + ((size_t)gy << 7) + lcol, &in_t[r0][0]);
            }
        }
        __syncthreads();
        // zero the out-of-volume halo rows (only edge slabs have any)
        if (y0 == 0 || y0 == 112) {
#pragma unroll
            for (int t = 0; t < 2; ++t) {
                int j = tid + t * NT;
                if (j < 704) {
                    int lr = j >> 5;
                    int gy = y0 - 3 + lr;
                    if (gy < 0 || gy > 127)
                        *(float4*)&in_t[lr][(j & 31) << 2] = f4zero();
                }
            }
        }
    } else {
        const float* u  = v + (size_t)n * 3 * VOX;
        const float* vv = u + VOX;
        const float* w  = vv + VOX;
        int dzo = (z < 127) ? 16384 : -16384;
        const float* b0 = w  + zoff;
        const float* b1 = u  + zoff;
        const float* b2 = vv + zoff;
        const float* b3 = vv + zoff + dzo;
        const float* b4 = u  + zoff + dzo;
        // ---- 60 row-pairs across 8 waves: every load async, zero VGPR held ----
#pragma unroll
        for (int t = 0; t < 8; ++t) {
            int pr = wid + (t << 3);
            if (pr < 60) {
                int buf = pr / 12;                 // uniform per wave
                int r0  = (pr - buf * 12) << 1;
                int gy  = y0 - 3 + r0 + lrow;
                gy = min(127, max(0, gy));
                const float* bp = (buf == 0) ? b0 : (buf == 1) ? b1
                                : (buf == 2) ? b2 : (buf == 3) ? b3 : b4;
                gll16(bp + ((size_t)gy << 7) + lcol,
                      stage + (((buf * 24) + r0) << 7));
            }
        }
        __syncthreads();   // drains vmcnt (gll queue) + joins waves

        // ---- |curl| from LDS into in_t (22 rows x 32 quads = 704 items) ----
        float sz = (z < 127) ? 1.f : -1.f;
        const float* sW  = stage;
        const float* sU  = stage + 24 * 128;
        const float* sVc = stage + 48 * 128;
        const float* sVz = stage + 72 * 128;
        const float* sUz = stage + 96 * 128;
#pragma unroll
        for (int t = 0; t < 2; ++t) {
            int j = tid + t * NT;
            if (j < 704) {
                int lr = j >> 5;
                int c4 = (j & 31) << 2;
                int gy = y0 - 3 + lr;
                float4 val;
                if (gy >= 0 && gy <= 127) {
                    int   ry = (gy < 127) ? lr + 1 : lr - 1;  // y-diff row (bwd at y=127)
                    float sy = (gy < 127) ? 1.f : -1.f;
                    int ro = lr << 7, ryo = ry << 7;
                    float4 wc  = *(const float4*)(sW  + ro  + c4);
                    float4 wy  = *(const float4*)(sW  + ryo + c4);
                    float4 uc  = *(const float4*)(sU  + ro  + c4);
                    float4 uy  = *(const float4*)(sU  + ryo + c4);
                    float4 vc  = *(const float4*)(sVc + ro  + c4);
                    float4 vzn = *(const float4*)(sVz + ro  + c4);
                    float4 uzn = *(const float4*)(sUz + ro  + c4);
                    float wxp = sW [ro + c4 + 4];   // in padded buffer, unused at c4==124
                    float vxp = sVc[ro + c4 + 4];
                    float wca[4] = {wc.x, wc.y, wc.z, wc.w};
                    float vca[4] = {vc.x, vc.y, vc.z, vc.w};
                    float wya[4] = {wy.x, wy.y, wy.z, wy.w};
                    float vza[4] = {vzn.x, vzn.y, vzn.z, vzn.w};
                    float uca[4] = {uc.x, uc.y, uc.z, uc.w};
                    float uza[4] = {uzn.x, uzn.y, uzn.z, uzn.w};
                    float uya[4] = {uy.x, uy.y, uy.z, uy.w};
                    float wsh[4] = {wc.y, wc.z, wc.w, wxp};
                    float vsh[4] = {vc.y, vc.z, vc.w, vxp};
                    float* oa = &val.x;
#pragma unroll
                    for (int j2 = 0; j2 < 4; ++j2) {
                        int x = c4 + j2;
                        float fdxw = (x < 127) ? (wsh[j2] - wca[j2]) : (wca[3] - wca[2]);
                        float fdxv = (x < 127) ? (vsh[j2] - vca[j2]) : (vca[3] - vca[2]);
                        float fdyw = sy * (wya[j2] - wca[j2]);
                        float fdyu = sy * (uya[j2] - uca[j2]);
                        float fdzv = sz * (vza[j2] - vca[j2]);
                        float fdzu = sz * (uza[j2] - uca[j2]);
                        float cu = fdyw - fdzv;
                        float cv = fdzu - fdxw;
                        float cw = fdxv - fdyu;
                        oa[j2] = sqrtf(cu * cu + cv * cv + cw * cw);
                    }
                } else val = f4zero();
                *(float4*)&in_t[lr][c4] = val;
            }
        }
    }
    __syncthreads();

    // y-conv: one float4 per thread (16 rows x 32 quads = 512 items)
    int yo = tid >> 5;
    int c4 = (tid & 31) << 2;
    float4 a = f4zero();
#pragma unroll
    for (int k = 0; k < 7; ++k) {
        float wk = gw.w[k];
        float4 tv = *(const float4*)&in_t[yo + k][c4];
        a.x += wk * tv.x; a.y += wk * tv.y; a.z += wk * tv.z; a.w += wk * tv.w;
    }
    __syncthreads();
    *(float4*)&in_t[yo][c4] = a;
    __syncthreads();

    // x-conv -> global, zero-pad at x edges via guarded LDS reads
    float* out = isCurl ? Q : P;
    float4 q0 = (c4 > 0)   ? *(const float4*)&in_t[yo][c4 - 4] : f4zero();
    float4 q1 =              *(const float4*)&in_t[yo][c4];
    float4 q2 = (c4 < 124) ? *(const float4*)&in_t[yo][c4 + 4] : f4zero();
    float wdw[11] = {q0.y, q0.z, q0.w,
                     q1.x, q1.y, q1.z, q1.w,
                     q2.x, q2.y, q2.z, q2.w};
    float o[4];
#pragma unroll
    for (int j2 = 0; j2 < 4; ++j2) {
        float acc = 0.f;
#pragma unroll
        for (int k = 0; k < 7; ++k) acc += gw.w[k] * wdw[j2 + k];
        o[j2] = acc;
    }
    *(float4*)(out + slice + ((size_t)(y0 + yo) << 7) + c4) =
        make_float4(o[0], o[1], o[2], o[3]);
}

// ---------------------------------------------------------------------------
// Render, 4-way z-chunk parallel (unchanged).
__global__ __launch_bounds__(256, 4)
void render_zs4_kernel(const float* __restrict__ P, const float* __restrict__ Q,
                       float* __restrict__ out, GaussW gw) {
    __shared__ float csum[4][64];
    __shared__ float part[4][64];

    int xl = threadIdx.x & 63;
    int ch = threadIdx.x >> 6;
    int col = blockIdx.x * 64 + xl;       // 1024 blocks * 64 = 65536 columns
    int x = col & 127;
    int y = (col >> 7) & 127;
    int n = col >> 14;
    size_t volbase = ((size_t)n << 21) | ((size_t)y << 7) | (size_t)x;
    int j0 = ch * 32;

    float a[38];
#pragma unroll
    for (int t = 0; t < 38; ++t) {
        int j = j0 - 3 + t;
        a[t] = (j >= 0 && j <= 127) ? P[volbase + ((size_t)(127 - j) << 14)] : 0.f;
    }
#pragma unroll
    for (int i = 0; i < 32; ++i) {
        float s = 0.f;
#pragma unroll
        for (int k = 0; k < 7; ++k) s += gw.w[k] * a[i + k];
        a[i] = s;
    }
    float S = 0.f;
#pragma unroll
    for (int i = 0; i < 32; ++i) S += a[i];
    csum[ch][xl] = S;

    float bq[39];
#pragma unroll
    for (int t = 0; t < 39; ++t) {
        int j = j0 - 4 + t;
        bq[t] = (j >= 0 && j <= 127) ? Q[volbase + ((size_t)(127 - j) << 14)] : 0.f;
    }
    __syncthreads();

    float offset = 0.f;
    if (ch > 0) offset += csum[0][xl];
    if (ch > 1) offset += csum[1][xl];
    if (ch > 2) offset += csum[2][xl];

    float tp = 0.f, vp = 0.f, acc = 0.f, xacc = offset;
    if (ch > 0) {
        float v0 = 0.f;
#pragma unroll
        for (int k = 0; k < 7; ++k) v0 += gw.w[k] * bq[k];   // vnf[j0-1]
        vp = v0;
        float xc = 20.f * offset;
        tp = (xc + 1.f) * __expf(-xc);
    }
#pragma unroll
    for (int i = 0; i < 32; ++i) {
        xacc += a[i];
        float vk = 0.f;
#pragma unroll
        for (int k = 0; k < 7; ++k) vk += gw.w[k] * bq[i + 1 + k];  // vnf[j0+i]
        float xc = 20.f * xacc;
        float tk = (xc + 1.f) * __expf(-xc);
        if (ch == 0 && i == 0) acc = (1.f - tk) * vk;
        else                   acc += (tp - tk) * (vp + vk) * 0.5f;
        tp = tk; vp = vk;
    }
    part[ch][xl] = acc;
    __syncthreads();

    if (ch == 0) {
        float r = part[0][xl] + part[1][xl] + part[2][xl] + part[3][xl];
        out[col] = fminf(fmaxf(r, 0.f), 1.f);
    }
}

// ---------------------------------------------------------------------------
extern "C" void kernel_launch(void* const* d_in, const int* in_sizes, int n_in,
                              void* d_out, int out_size, void* d_ws, size_t ws_size,
                              hipStream_t stream) {
    const float* d = (const float*)d_in[0];   // (4,1,128,128,128)
    const float* v = (const float*)d_in[1];   // (4,3,128,128,128)
    float* out = (float*)d_out;               // (4,1,128,128)

    GaussW gw;
    {
        double g[7], s = 0.0;
        for (int i = 0; i < 7; ++i) {
            double t = (i - 3) / 1.6;
            g[i] = exp(-t * t / 2.0);
            s += g[i];
        }
        for (int i = 0; i < 7; ++i) gw.w[i] = (float)(g[i] / s);
    }

    float* ws0 = (float*)d_ws;        // P = yx-smoothed d
    float* ws1 = ws0 + NVOX;          // Q = yx-smoothed |curl|

    // 1) fused: d yx-smooth (blocks 0-4095) + LDS-staged curl yx-smooth (4096-8191)
    yx_curl_dual_kernel<<<2 * NB * DD * 8, 512, 0, stream>>>(d, ws0, v, ws1, gw);

    // 2) render: 4-way z-chunk parallel with LDS scan + on-the-fly z-smooth
    render_zs4_kernel<<<(NB * HH * WW) / 64, 256, 0, stream>>>(ws0, ws1, out, gw);
}